// Round 1
// baseline (1167.326 us; speedup 1.0000x reference)
//
#include <hip/hip_runtime.h>

// Irreps: 256x0e + 128x1o + 64x2e + 32x3o
// out[n, XO_l + w*d + i] = (1/m) * sum_u x[n, XO_l + u*d + i] * weight[n, WO_l + u] * W_l[u, w]
// Strategy: fold 1/m into a bf16 pre-swizzled copy of W (prologue kernel, L2-resident),
// stage A = x*weight as bf16 in LDS per 16-row chunk, mfma_f32_16x16x32_bf16.

typedef short  bf16x8 __attribute__((ext_vector_type(8)));
typedef float  f32x4  __attribute__((ext_vector_type(4)));

#define DIM  1184
#define WNUM 480

// Pre-swizzled bf16 W (already scaled by 1/m), in MFMA B-fragment order:
// fragment f holds 64 lanes x 8 bf16; lane L, elem j = W[(k0*32 + (L>>4)*8 + j)*m + c*16 + (L&15)]/m
// frag bases: l0: 0 (8 k-steps x 16 col-tiles = 128), l1: 128 (4x8=32), l2: 160 (2x4=8), l3: 168 (1x2=2)
__device__ __align__(16) unsigned short g_wswz[170 * 512];

__device__ __forceinline__ unsigned short f2bf(float v) {
    union { float f; unsigned u; } a; a.f = v;
    unsigned u = a.u + 0x7FFFu + ((a.u >> 16) & 1u);   // round-to-nearest-even
    return (unsigned short)(u >> 16);
}

__global__ void prep_w(const float* __restrict__ W0, const float* __restrict__ W1,
                       const float* __restrict__ W2, const float* __restrict__ W3) {
    const int f = blockIdx.x;
    const int lane = threadIdx.x;
    const float* W; int m, k0, c;
    if (f < 128)      { W = W0; m = 256; int lo = f;       k0 = lo >> 4; c = lo & 15; }
    else if (f < 160) { W = W1; m = 128; int lo = f - 128; k0 = lo >> 3; c = lo & 7;  }
    else if (f < 168) { W = W2; m = 64;  int lo = f - 160; k0 = lo >> 2; c = lo & 3;  }
    else              { W = W3; m = 32;  int lo = f - 168; k0 = lo >> 1; c = lo & 1;  }
    const float inv = 1.0f / (float)m;
    const int krow = k0 * 32 + (lane >> 4) * 8;
    const int col  = c * 16 + (lane & 15);
    unsigned short* dst = &g_wswz[f * 512 + lane * 8];
#pragma unroll
    for (int j = 0; j < 8; ++j)
        dst[j] = f2bf(W[(krow + j) * m + col] * inv);
}

// LDS layout (ushort elems): per block l, d tiles of [16 rows x (m+8)] (pad keeps 16B align, 2-way-free banks)
// l0: base 0,     stride 264, 16 rows  -> 4224
// l1: base 4224,  stride 136, 48 rows  -> 6528
// l2: base 10752, stride 72,  80 rows  -> 5760
// l3: base 16512, stride 40, 112 rows  -> 4480   total 20992 ushort = 41984 B (~3 WGs/CU)

template<int M, int D, int NTC, int NK, int FBASE, int ABASE, int STRIDE, int XO>
__device__ __forceinline__ void do_block(const unsigned short* Alds, float* __restrict__ out,
                                         int n0, int n, int lane, int wv) {
    const int r = lane & 15, q = lane >> 4;
    for (int c = wv; c < NTC; c += 4) {
        f32x4 acc[D];
#pragma unroll
        for (int i = 0; i < D; ++i) acc[i] = f32x4{0.f, 0.f, 0.f, 0.f};
#pragma unroll
        for (int k0 = 0; k0 < NK; ++k0) {
            const bf16x8 b = *reinterpret_cast<const bf16x8*>(
                &g_wswz[(FBASE + k0 * NTC + c) * 512 + lane * 8]);
#pragma unroll
            for (int i = 0; i < D; ++i) {
                const bf16x8 a = *reinterpret_cast<const bf16x8*>(
                    &Alds[ABASE + (i * 16 + r) * STRIDE + k0 * 32 + q * 8]);
                acc[i] = __builtin_amdgcn_mfma_f32_16x16x32_bf16(a, b, acc[i], 0, 0, 0);
            }
        }
#pragma unroll
        for (int i = 0; i < D; ++i) {
#pragma unroll
            for (int g = 0; g < 4; ++g) {
                const int row = n0 + q * 4 + g;
                if (row < n)
                    out[row * DIM + XO + (c * 16 + r) * D + i] = acc[i][g];
            }
        }
    }
}

__global__ __launch_bounds__(256) void main_k(const float* __restrict__ x,
                                              const float* __restrict__ w,
                                              float* __restrict__ out, int n) {
    __shared__ __align__(16) unsigned short Alds[20992];
    const int tid = threadIdx.x;
    const int n0  = blockIdx.x * 16;

    // ---- stage 1: A = x * weight -> bf16 LDS (coalesced float4 x-loads) ----
    const float* xbase = x + (long)n0 * DIM;
    for (int fidx = tid; fidx < 4736; fidx += 256) {       // 16 rows x 296 float4
        const int nl = fidx / 296;
        if (n0 + nl >= n) continue;
        const int c0 = (fidx - nl * 296) * 4;
        const float4 xv = *reinterpret_cast<const float4*>(&xbase[nl * DIM + c0]);
        const float* wrow = w + (n0 + nl) * WNUM;
#pragma unroll
        for (int e = 0; e < 4; ++e) {
            const int c = c0 + e;
            const float xe = (&xv.x)[e];
            int aoff, woff;
            if (c < 256)      { const int u = c;                            aoff = 0     + (0 * 16 + nl) * 264 + u;              woff = u; }
            else if (c < 640) { const int t = c - 256; const int u = t / 3; aoff = 4224  + ((t - u * 3) * 16 + nl) * 136 + u;    woff = 256 + u; }
            else if (c < 960) { const int t = c - 640; const int u = t / 5; aoff = 10752 + ((t - u * 5) * 16 + nl) * 72  + u;    woff = 384 + u; }
            else              { const int t = c - 960; const int u = t / 7; aoff = 16512 + ((t - u * 7) * 16 + nl) * 40  + u;    woff = 448 + u; }
            Alds[aoff] = f2bf(xe * wrow[woff]);
        }
    }
    __syncthreads();

    // ---- stage 2: MFMA per block ----
    const int lane = tid & 63, wv = tid >> 6;
    do_block<256, 1, 16, 8,   0,     0, 264,   0>(Alds, out, n0, n, lane, wv);
    do_block<128, 3,  8, 4, 128,  4224, 136, 256>(Alds, out, n0, n, lane, wv);
    do_block< 64, 5,  4, 2, 160, 10752,  72, 640>(Alds, out, n0, n, lane, wv);
    do_block< 32, 7,  2, 1, 168, 16512,  40, 960>(Alds, out, n0, n, lane, wv);
}

extern "C" void kernel_launch(void* const* d_in, const int* in_sizes, int n_in,
                              void* d_out, int out_size, void* d_ws, size_t ws_size,
                              hipStream_t stream) {
    const float* x  = (const float*)d_in[0];
    const float* wt = (const float*)d_in[1];
    const int n = in_sizes[0] / DIM;          // 100000
    prep_w<<<dim3(170), dim3(64), 0, stream>>>((const float*)d_in[2], (const float*)d_in[3],
                                               (const float*)d_in[4], (const float*)d_in[5]);
    main_k<<<dim3((n + 15) / 16), dim3(256), 0, stream>>>(x, wt, (float*)d_out, n);
}